// Round 1
// baseline (220.531 us; speedup 1.0000x reference)
//
#include <hip/hip_runtime.h>

typedef float f32x4 __attribute__((ext_vector_type(4)));
typedef short s16x8 __attribute__((ext_vector_type(8)));
typedef unsigned short u16x8 __attribute__((ext_vector_type(8)));

#define DM   1024
#define LSEQ 2048
#define NH   16
#define HD   64
#define MTOT 4096   // B * LSEQ

__device__ __forceinline__ unsigned short f2bf(float f) {
  union { float f; unsigned int u; } v; v.f = f;
  unsigned int r = (v.u + 0x7fffu + ((v.u >> 16) & 1u)) >> 16;
  return (unsigned short)r;
}

// ---------------- x fp32 -> bf16 ----------------
__global__ __launch_bounds__(256) void xconv(const float* __restrict__ x,
                                             unsigned short* __restrict__ xb) {
  long i = ((long)blockIdx.x * 256 + threadIdx.x) * 8;
  float4 a = *(const float4*)&x[i];
  float4 b = *(const float4*)&x[i + 4];
  u16x8 o;
  o[0] = f2bf(a.x); o[1] = f2bf(a.y); o[2] = f2bf(a.z); o[3] = f2bf(a.w);
  o[4] = f2bf(b.x); o[5] = f2bf(b.y); o[6] = f2bf(b.z); o[7] = f2bf(b.w);
  *(u16x8*)&xb[i] = o;
}

// ---------------- W [K][N] fp32 -> Wt [N][K] bf16 (LDS tile transpose) ----------------
__global__ __launch_bounds__(256) void wtrans(const float* __restrict__ W,
                                              unsigned short* __restrict__ Wt) {
  __shared__ __align__(16) unsigned short t[64][72];
  const int n0 = blockIdx.x * 64, k0 = blockIdx.y * 64;
  const int r = threadIdx.x >> 4, c4 = (threadIdx.x & 15) * 4;
#pragma unroll
  for (int rr = r; rr < 64; rr += 16) {
    float4 v = *(const float4*)&W[(long)(k0 + rr) * DM + n0 + c4];
    ushort4 u;
    u.x = f2bf(v.x); u.y = f2bf(v.y); u.z = f2bf(v.z); u.w = f2bf(v.w);
    *(ushort4*)&t[rr][c4] = u;
  }
  __syncthreads();
#pragma unroll
  for (int rr = r; rr < 64; rr += 16) {
    ushort4 u;
    u.x = t[c4 + 0][rr]; u.y = t[c4 + 1][rr];
    u.z = t[c4 + 2][rr]; u.w = t[c4 + 3][rr];
    *(ushort4*)&Wt[(long)(n0 + rr) * DM + k0 + c4] = u;
  }
}

// ---------------- GEMM: C[M][N] = A[M][K](bf16) * Bt[N][K]^T (bf16) + bias ----------------
// 128x128 tile, BK=64, 4 waves of 64x64, mfma 16x16x32 bf16.
template <int QKV_MODE>
__global__ __launch_bounds__(256) void gemm_bt(
    const unsigned short* __restrict__ A, const unsigned short* __restrict__ Bt,
    const float* __restrict__ bias0, const float* __restrict__ bias1,
    const float* __restrict__ bias2, void* __restrict__ Cout, int N, int K) {
  __shared__ __align__(16) unsigned short As[128][72];
  __shared__ __align__(16) unsigned short Bs[128][72];
  const int tid = threadIdx.x;
  const int lane = tid & 63, w = tid >> 6;
  const int r16 = lane & 15, g = lane >> 4;
  const int m0 = blockIdx.y * 128, n0 = blockIdx.x * 128;
  const int wm = (w >> 1) * 64, wn = (w & 1) * 64;
  const int srow = tid >> 2, scol = (tid & 3) * 8;
  f32x4 acc[4][4] = {};
  for (int kt = 0; kt < K; kt += 64) {
    const unsigned short* Ag = A + (long)(m0 + srow) * K + kt + scol;
    const unsigned short* Bg = Bt + (long)(n0 + srow) * K + kt + scol;
    s16x8 a0 = *(const s16x8*)Ag;
    s16x8 a1 = *(const s16x8*)(Ag + 32);
    s16x8 a2 = *(const s16x8*)(Ag + 64L * K);
    s16x8 a3 = *(const s16x8*)(Ag + 64L * K + 32);
    s16x8 b0 = *(const s16x8*)Bg;
    s16x8 b1 = *(const s16x8*)(Bg + 32);
    s16x8 b2 = *(const s16x8*)(Bg + 64L * K);
    s16x8 b3 = *(const s16x8*)(Bg + 64L * K + 32);
    __syncthreads();  // protect LDS from previous iteration's readers
    *(s16x8*)&As[srow][scol]           = a0;
    *(s16x8*)&As[srow][scol + 32]      = a1;
    *(s16x8*)&As[srow + 64][scol]      = a2;
    *(s16x8*)&As[srow + 64][scol + 32] = a3;
    *(s16x8*)&Bs[srow][scol]           = b0;
    *(s16x8*)&Bs[srow][scol + 32]      = b1;
    *(s16x8*)&Bs[srow + 64][scol]      = b2;
    *(s16x8*)&Bs[srow + 64][scol + 32] = b3;
    __syncthreads();
#pragma unroll
    for (int kk = 0; kk < 64; kk += 32) {
      s16x8 af[4], bf[4];
#pragma unroll
      for (int i = 0; i < 4; i++) af[i] = *(const s16x8*)&As[wm + i * 16 + r16][kk + g * 8];
#pragma unroll
      for (int j = 0; j < 4; j++) bf[j] = *(const s16x8*)&Bs[wn + j * 16 + r16][kk + g * 8];
#pragma unroll
      for (int i = 0; i < 4; i++)
#pragma unroll
        for (int j = 0; j < 4; j++)
          acc[i][j] = __builtin_amdgcn_mfma_f32_16x16x32_bf16(af[i], bf[j], acc[i][j], 0, 0, 0);
    }
  }
#pragma unroll
  for (int i = 0; i < 4; i++) {
#pragma unroll
    for (int j = 0; j < 4; j++) {
      const int row = m0 + wm + i * 16 + g * 4;
      const int col = n0 + wn + j * 16 + r16;
      float bb;
      if constexpr (QKV_MODE)
        bb = (col < 1024) ? bias0[col] : (col < 2048) ? bias1[col - 1024] : bias2[col - 2048];
      else
        bb = bias0[col];
#pragma unroll
      for (int r = 0; r < 4; r++) {
        float v = acc[i][j][r] + bb;
        if constexpr (QKV_MODE)
          ((unsigned short*)Cout)[(long)(row + r) * N + col] = f2bf(v);
        else
          ((float*)Cout)[(long)(row + r) * N + col] = v;
      }
    }
  }
}

// ---------------- flash attention ----------------
// grid: (LSEQ/64 q-blocks, B*NH). 256 threads; wave w owns 16 q-rows.
__global__ __launch_bounds__(256) void attn(const unsigned short* __restrict__ QKV,
                                            unsigned short* __restrict__ O) {
  __shared__ __align__(16) unsigned short Ks[64][72];
  __shared__ __align__(16) unsigned short Vt[64][72];
  __shared__ __align__(16) unsigned short Ps[4][16][72];
  const int tid = threadIdx.x;
  const int lane = tid & 63, w = tid >> 6;
  const int r16 = lane & 15, g = lane >> 4;
  const int qb = blockIdx.x, bh = blockIdx.y;
  const int b = bh >> 4, h = bh & 15;
  const long RS = 3 * DM;
  const unsigned short* Qg = QKV + (long)(b * LSEQ + qb * 64 + w * 16 + r16) * RS + h * HD;
  const s16x8 qa0 = *(const s16x8*)&Qg[g * 8];
  const s16x8 qa1 = *(const s16x8*)&Qg[32 + g * 8];
  const unsigned short* Kb = QKV + (long)(b * LSEQ) * RS + DM + h * HD;
  const unsigned short* Vb = Kb + DM;
  const int srow = tid >> 2, scol = (tid & 3) * 8;
  f32x4 o[4] = {};
  float m_run[4], l_run[4];
#pragma unroll
  for (int r = 0; r < 4; r++) { m_run[r] = -1e30f; l_run[r] = 0.f; }

  for (int kt = 0; kt < LSEQ; kt += 64) {
    const long gro = (long)(kt + srow) * RS + scol;
    s16x8 k0 = *(const s16x8*)&Kb[gro];
    s16x8 k1 = *(const s16x8*)&Kb[gro + 32];
    s16x8 v0 = *(const s16x8*)&Vb[gro];
    s16x8 v1 = *(const s16x8*)&Vb[gro + 32];
    __syncthreads();  // previous iteration's PV reads done
    *(s16x8*)&Ks[srow][scol]      = k0;
    *(s16x8*)&Ks[srow][scol + 32] = k1;
#pragma unroll
    for (int j = 0; j < 8; j++) {
      Vt[scol + j][srow]      = (unsigned short)v0[j];
      Vt[scol + 32 + j][srow] = (unsigned short)v1[j];
    }
    __syncthreads();

    // S = Q K^T  (both operands want 8 contiguous d-elems/lane: no transpose)
    f32x4 s[4];
#pragma unroll
    for (int kc = 0; kc < 4; kc++) {
      s16x8 kb0 = *(const s16x8*)&Ks[kc * 16 + r16][g * 8];
      s16x8 kb1 = *(const s16x8*)&Ks[kc * 16 + r16][32 + g * 8];
      f32x4 z = {};
      z = __builtin_amdgcn_mfma_f32_16x16x32_bf16(qa0, kb0, z, 0, 0, 0);
      s[kc] = __builtin_amdgcn_mfma_f32_16x16x32_bf16(qa1, kb1, z, 0, 0, 0);
    }

    // online softmax; row r of this lane = 4*g + r, cols = kc*16 + (lane&15)
#pragma unroll
    for (int r = 0; r < 4; r++) {
#pragma unroll
      for (int kc = 0; kc < 4; kc++) s[kc][r] *= 0.125f;
      float tm = fmaxf(fmaxf(s[0][r], s[1][r]), fmaxf(s[2][r], s[3][r]));
      tm = fmaxf(tm, __shfl_xor(tm, 1));
      tm = fmaxf(tm, __shfl_xor(tm, 2));
      tm = fmaxf(tm, __shfl_xor(tm, 4));
      tm = fmaxf(tm, __shfl_xor(tm, 8));
      float nm = fmaxf(m_run[r], tm);
      float alpha = __expf(m_run[r] - nm);
      m_run[r] = nm;
      float sum = 0.f;
#pragma unroll
      for (int kc = 0; kc < 4; kc++) {
        float p = __expf(s[kc][r] - nm);
        s[kc][r] = p;
        sum += p;
      }
      sum += __shfl_xor(sum, 1);
      sum += __shfl_xor(sum, 2);
      sum += __shfl_xor(sum, 4);
      sum += __shfl_xor(sum, 8);
      l_run[r] = l_run[r] * alpha + sum;
#pragma unroll
      for (int dc = 0; dc < 4; dc++) o[dc][r] *= alpha;
    }

    // P -> per-wave LDS buffer (re-fragment for PV A-operand)
#pragma unroll
    for (int kc = 0; kc < 4; kc++)
#pragma unroll
      for (int r = 0; r < 4; r++)
        Ps[w][g * 4 + r][kc * 16 + r16] = f2bf(s[kc][r]);
    asm volatile("s_waitcnt lgkmcnt(0)" ::: "memory");

    // O += P V
#pragma unroll
    for (int t = 0; t < 2; t++) {
      s16x8 pa = *(const s16x8*)&Ps[w][r16][t * 32 + g * 8];
#pragma unroll
      for (int dc = 0; dc < 4; dc++) {
        s16x8 vb = *(const s16x8*)&Vt[dc * 16 + r16][t * 32 + g * 8];
        o[dc] = __builtin_amdgcn_mfma_f32_16x16x32_bf16(pa, vb, o[dc], 0, 0, 0);
      }
    }
  }

  unsigned short* Og = O + (long)(b * LSEQ + qb * 64 + w * 16) * DM + h * HD;
#pragma unroll
  for (int r = 0; r < 4; r++) {
    float inv = 1.0f / l_run[r];
#pragma unroll
    for (int dc = 0; dc < 4; dc++)
      Og[(long)(g * 4 + r) * DM + dc * 16 + r16] = f2bf(o[dc][r] * inv);
  }
}

extern "C" void kernel_launch(void* const* d_in, const int* in_sizes, int n_in,
                              void* d_out, int out_size, void* d_ws, size_t ws_size,
                              hipStream_t stream) {
  const float* x  = (const float*)d_in[0];
  const float* Wq = (const float*)d_in[1];
  const float* bq = (const float*)d_in[2];
  const float* Wk = (const float*)d_in[3];
  const float* bk = (const float*)d_in[4];
  const float* Wv = (const float*)d_in[5];
  const float* bv = (const float*)d_in[6];
  const float* Wo = (const float*)d_in[7];
  const float* bo = (const float*)d_in[8];

  unsigned short* xb   = (unsigned short*)d_ws;            // 4096*1024 bf16
  unsigned short* Wcat = xb + (size_t)MTOT * DM;           // 3072*1024 bf16 (Wq^T|Wk^T|Wv^T)
  unsigned short* Wot  = Wcat + (size_t)3 * DM * DM;       // 1024*1024 bf16
  unsigned short* QKVb = Wot + (size_t)DM * DM;            // 4096*3072 bf16
  unsigned short* Ob   = QKVb + (size_t)MTOT * 3 * DM;     // 4096*1024 bf16

  xconv<<<(MTOT * DM) / (256 * 8), 256, 0, stream>>>(x, xb);
  wtrans<<<dim3(16, 16), 256, 0, stream>>>(Wq, Wcat);
  wtrans<<<dim3(16, 16), 256, 0, stream>>>(Wk, Wcat + (size_t)DM * DM);
  wtrans<<<dim3(16, 16), 256, 0, stream>>>(Wv, Wcat + (size_t)2 * DM * DM);
  wtrans<<<dim3(16, 16), 256, 0, stream>>>(Wo, Wot);

  gemm_bt<1><<<dim3(3 * DM / 128, MTOT / 128), 256, 0, stream>>>(
      xb, Wcat, bq, bk, bv, (void*)QKVb, 3 * DM, DM);
  attn<<<dim3(LSEQ / 64, 2 * NH), 256, 0, stream>>>(QKVb, Ob);
  gemm_bt<0><<<dim3(DM / 128, MTOT / 128), 256, 0, stream>>>(
      Ob, Wot, bo, nullptr, nullptr, d_out, DM, DM);
}